// Round 6
// baseline (3291.687 us; speedup 1.0000x reference)
//
#include <hip/hip_runtime.h>
#include <cmath>

// BiDirectionalSpatialMamba: lin+GELU -> GRU(fwd & bwd over P) -> proj+residual -> LN
// B=8 T=16 P=1024 H=256, D_INNER=512, 3H=768. M = B*T*P = 131072 rows.

typedef _Float16 h8  __attribute__((ext_vector_type(8)));
typedef _Float16 h2v __attribute__((ext_vector_type(2)));
typedef float    f32x4 __attribute__((ext_vector_type(4)));

#define MTOT 131072L
#define PSEQ 1024

__device__ __forceinline__ float fast_sigmoid(float x) {
    float e = __builtin_amdgcn_exp2f(-1.44269504089f * x);
    return __builtin_amdgcn_rcpf(1.f + e);
}
__device__ __forceinline__ float fast_tanh(float x) {
    float e = __builtin_amdgcn_exp2f(-2.88539008178f * x);
    return (1.f - e) * __builtin_amdgcn_rcpf(1.f + e);
}

// ---------------- GEMM: C[M x N] = A[M x K] @ B[K x N] + bias, f16 MFMA ----------
// MODE 0: A fp32 (x),   K=256 N=512, epilogue GELU(exact) -> f16 (h1)
// MODE 1: A f16 (h1),   K=512 N=768, epilogue +bias -> f16 gi, GRU-permuted layout
//         (scatter uses GLOBAL row = chunk-local row + m_off  — round-5 bugfix)
// MODE 2: A cat f16,    K=512 N=256, epilogue +b +x -> f32 (pre-LN)
template <int MODE>
__global__ __launch_bounds__(256) void k_gemm(
    const void* __restrict__ Aa_, const void* __restrict__ Ab_,
    const float* __restrict__ B, const float* __restrict__ bias,
    const float* __restrict__ xres, void* __restrict__ out_, long m_off)
{
    constexpr int K = (MODE == 0) ? 256 : 512;
    constexpr int N = (MODE == 0) ? 512 : (MODE == 1 ? 768 : 256);

    __shared__ __align__(16) _Float16 Al[64][40];  // [m][k], pad 32->40 (bank spread)
    __shared__ __align__(16) _Float16 Bl[64][40];  // [n][k]

    const int tid  = threadIdx.x;
    const int lane = tid & 63;
    const int wave = tid >> 6;
    const int wm = wave >> 1, wn = wave & 1;
    // MODE 1: x = N-blocks, y = M-blocks
    const long bm0 = (long)(MODE == 1 ? blockIdx.y : blockIdx.x) * 64;
    const int  bn0 = (MODE == 1 ? blockIdx.x : blockIdx.y) * 64;

    const int sm  = tid >> 2;          // A staging: row
    const int ska = (tid & 3) * 8;     // A staging: k offset
    const int sn  = tid & 63;          // B staging: col
    const int skb = (tid >> 6) * 8;    // B staging: k offset

    f32x4 acc[2][2] = {};

    for (int kt = 0; kt < K / 32; ++kt) {
        h8 av;
        if constexpr (MODE == 0) {
            const float* ap = (const float*)Aa_ + (bm0 + sm) * 256 + kt * 32 + ska;
            #pragma unroll
            for (int i = 0; i < 8; ++i) av[i] = (_Float16)ap[i];
        } else if constexpr (MODE == 1) {
            av = *(const h8*)((const _Float16*)Aa_ + (bm0 + sm) * 512 + kt * 32 + ska);
        } else {
            const _Float16* src = (kt < 8) ? (const _Float16*)Aa_ : (const _Float16*)Ab_;
            av = *(const h8*)(src + (bm0 + sm) * 256 + (kt & 7) * 32 + ska);
        }
        *(h8*)&Al[sm][ska] = av;

        h8 bv;
        #pragma unroll
        for (int i = 0; i < 8; ++i)
            bv[i] = (_Float16)B[(long)(kt * 32 + skb + i) * N + bn0 + sn];
        *(h8*)&Bl[sn][skb] = bv;

        __syncthreads();

        const int fr = lane & 15, fg = lane >> 4;
        h8 a0 = *(const h8*)&Al[wm * 32 +      fr][fg * 8];
        h8 a1 = *(const h8*)&Al[wm * 32 + 16 + fr][fg * 8];
        h8 b0 = *(const h8*)&Bl[wn * 32 +      fr][fg * 8];
        h8 b1 = *(const h8*)&Bl[wn * 32 + 16 + fr][fg * 8];
        acc[0][0] = __builtin_amdgcn_mfma_f32_16x16x32_f16(a0, b0, acc[0][0], 0, 0, 0);
        acc[0][1] = __builtin_amdgcn_mfma_f32_16x16x32_f16(a0, b1, acc[0][1], 0, 0, 0);
        acc[1][0] = __builtin_amdgcn_mfma_f32_16x16x32_f16(a1, b0, acc[1][0], 0, 0, 0);
        acc[1][1] = __builtin_amdgcn_mfma_f32_16x16x32_f16(a1, b1, acc[1][1], 0, 0, 0);

        __syncthreads();
    }

    const int fr = lane & 15, fg = lane >> 4;
    #pragma unroll
    for (int fm = 0; fm < 2; ++fm)
    #pragma unroll
    for (int fn = 0; fn < 2; ++fn)
    #pragma unroll
    for (int r = 0; r < 4; ++r) {
        long row = bm0 + wm * 32 + fm * 16 + fg * 4 + r;
        int  col = bn0 + wn * 32 + fn * 16 + fr;
        float v = acc[fm][fn][r] + bias[col];
        if constexpr (MODE == 0) {
            v = 0.5f * v * (1.0f + erff(v * 0.70710678118654752f));
            ((_Float16*)out_)[row * (long)N + col] = (_Float16)v;
        } else if constexpr (MODE == 1) {
            // scatter to GRU-permuted gi layout (bijective), GLOBAL rows:
            // [blk][p][g][thread(512)][e(8)] f16
            long grow = row + m_off;
            int seq = (int)(grow >> 10), p = (int)(grow & 1023);
            int blk = seq >> 4, srow = seq & 15;
            int g = col >> 8, ci = col & 255;
            int wv = ci >> 5, tp = (ci >> 4) & 1;
            int ln = (ci & 15) | ((srow >> 2) << 4);
            int e = tp * 4 + (srow & 3);
            long oidx = (((long)(blk * 1024 + p) * 3 + g) * 512 + (wv * 64 + ln)) * 8 + e;
            ((_Float16*)out_)[oidx] = (_Float16)v;
        } else {
            v += xres[row * 256 + col];
            ((float*)out_)[row * 256 + col] = v;
        }
    }
}

// ---------------- prep: W_hh fp32 [256][768] -> MFMA B-fragment layout f16 --------
// frag f = (w*6 + (g*2+tp))*8+kt ; out[f*64+l][i] = Whh[kt*32+(l>>4)*8+i][g*256+w*32+tp*16+(l&15)]
__global__ __launch_bounds__(256) void k_prep_frag(
    const float* __restrict__ Whh, _Float16* __restrict__ Wp)
{
    const int t = blockIdx.x * 256 + threadIdx.x;   // < 24576
    const int l = t & 63, f = t >> 6;               // f < 384
    const int kt = f & 7;
    const int q  = f >> 3;          // < 48
    const int tp = q & 1;
    const int q2 = q >> 1;          // < 24
    const int g  = q2 % 3, w = q2 / 3;
    const int col = g * 256 + w * 32 + tp * 16 + (l & 15);
    const int k0  = kt * 32 + (l >> 4) * 8;
    h8 v;
    #pragma unroll
    for (int i = 0; i < 8; ++i)
        v[i] = (_Float16)Whh[(long)(k0 + i) * 768 + col];
    ((h8*)Wp)[t] = v;
}

// bc[col] = b_ih[col] + (col<512 ? b_hh[col] : 0)  (n-gate b_hh applied inside GRU)
__global__ __launch_bounds__(256) void k_prep_bias(
    const float* __restrict__ bih, const float* __restrict__ bhh, float* __restrict__ bc)
{
    const int c = blockIdx.x * 256 + threadIdx.x;   // < 768
    bc[c] = bih[c] + (c < 512 ? bhh[c] : 0.f);
}

// ---------------- GRU recurrence v3: MFMA, 16 blocks x 512 threads ----------------
// Block = 16 same-direction sequences. Per step: h[16x256] @ W[256x768] via
// 48 MFMA/wave (8 waves, 2/SIMD, 256-reg unified budget).
// Register budget fix vs v2 (which needed ~300 regs -> spilled):
//   r,z gate B-fragments: 32 x h8 = 128 VGPRs (resident, MFMA reads directly)
//   n  gate B-fragments: 128KB LDS, ds_read_b128 per (tp,kt) inline
//   => ~205 regs, no spill. LDS total ~145KB (1 block/CU; only 16 blocks anyway).
// gi pre-permuted -> 3 x h8 global loads/thread/step, latency hidden by MFMA phase.
// ONE barrier per step.
__global__ __launch_bounds__(512, 2) void k_gru2(
    const _Float16* __restrict__ gpf, const _Float16* __restrict__ gpb,
    const _Float16* __restrict__ Wpf, const _Float16* __restrict__ Wpb,
    const float* __restrict__ bhhf, const float* __restrict__ bhhb,
    _Float16* __restrict__ hof, _Float16* __restrict__ hob)
{
    const int b = blockIdx.x;        // 16
    const int dir = b & 1;
    const int blk = b >> 1;          // seq-group [0,8)
    const int t = threadIdx.x;       // 512
    const int w = t >> 6, l = t & 63;
    const int lr = l & 15, lq = l >> 4;

    const _Float16* gp  = dir ? gpb : gpf;
    const _Float16* Wp  = dir ? Wpb : Wpf;
    const float*    bhh = dir ? bhhb : bhhf;
    _Float16*       hoo = dir ? hob : hof;

    __shared__ __align__(16) h8 wn_lds[8192];            // n-gate W frags [w][tp][kt][l] 128KB
    __shared__ __align__(16) _Float16 hbuf[2][16][264];  // dbuf h, pad 256->264

    // r,z B-fragments resident in VGPRs; n-gate staged to LDS
    h8 bfrz[2][2][8];
    {
        const h8* src = (const h8*)Wp + (long)w * 48 * 64 + l;
        #pragma unroll
        for (int g = 0; g < 2; ++g)
        #pragma unroll
        for (int tp = 0; tp < 2; ++tp)
        #pragma unroll
        for (int kt = 0; kt < 8; ++kt)
            bfrz[g][tp][kt] = src[((g * 2 + tp) * 8 + kt) * 64];
        #pragma unroll
        for (int tp = 0; tp < 2; ++tp)
        #pragma unroll
        for (int kt = 0; kt < 8; ++kt)
            wn_lds[((w * 2 + tp) * 8 + kt) * 64 + l] = src[((4 + tp) * 8 + kt) * 64];
    }
    const int col0 = w * 32 + lr;                  // thread's h-col (tp=0)
    const float bn0 = bhh[512 + col0];
    const float bn1 = bhh[512 + col0 + 16];

    for (int i = t; i < 2 * 16 * 264; i += 512) ((_Float16*)hbuf)[i] = (_Float16)0.f;
    __syncthreads();

    const int d = dir ? -1 : 1;
    int p = dir ? (PSEQ - 1) : 0;
    int cur = 0;
    const long tbase = (long)t * 8;
    const long bbase = (long)blk * 1024;
    float hold[2][4] = {};

    for (int step = 0; step < PSEQ; ++step) {
        // gi for current p; consumed after the MFMA phase (latency hidden)
        h8 gv0 = *(const h8*)(gp + ((bbase + p) * 3 + 0) * 4096 + tbase);
        h8 gv1 = *(const h8*)(gp + ((bbase + p) * 3 + 1) * 4096 + tbase);
        h8 gv2 = *(const h8*)(gp + ((bbase + p) * 3 + 2) * 4096 + tbase);

        f32x4 acc[3][2] = {};
        #pragma unroll
        for (int kt = 0; kt < 8; ++kt) {
            h8 af = *(const h8*)&hbuf[cur][lr][kt * 32 + lq * 8];
            #pragma unroll
            for (int tp = 0; tp < 2; ++tp) {
                acc[0][tp] = __builtin_amdgcn_mfma_f32_16x16x32_f16(af, bfrz[0][tp][kt], acc[0][tp], 0, 0, 0);
                acc[1][tp] = __builtin_amdgcn_mfma_f32_16x16x32_f16(af, bfrz[1][tp][kt], acc[1][tp], 0, 0, 0);
                h8 bfn = wn_lds[((w * 2 + tp) * 8 + kt) * 64 + l];
                acc[2][tp] = __builtin_amdgcn_mfma_f32_16x16x32_f16(af, bfn, acc[2][tp], 0, 0, 0);
            }
        }

        // in-register activations; write h to other LDS buffer + global
        #pragma unroll
        for (int tp = 0; tp < 2; ++tp) {
            const int col = col0 + tp * 16;
            const float bn = tp ? bn1 : bn0;
            #pragma unroll
            for (int r = 0; r < 4; ++r) {
                const int e = tp * 4 + r;
                float rr = fast_sigmoid(acc[0][tp][r] + (float)gv0[e]);
                float zz = fast_sigmoid(acc[1][tp][r] + (float)gv1[e]);
                float nh = acc[2][tp][r] + bn;
                float nn = fast_tanh((float)gv2[e] + rr * nh);
                float h  = fmaf(zz, hold[tp][r] - nn, nn);
                hold[tp][r] = h;
                _Float16 hf = (_Float16)h;
                const int row = lq * 4 + r;
                hbuf[cur ^ 1][row][col] = hf;
                hoo[((long)(blk * 16 + row) * PSEQ + p) * 256 + col] = hf;
            }
        }
        __syncthreads();   // h[cur^1] complete before next step's A-reads

        cur ^= 1; p += d;
    }
}

// ---------------- LayerNorm over H=256, wave per row ------------------------------
__global__ __launch_bounds__(256) void k_ln(
    const float* __restrict__ pre, const float* __restrict__ g,
    const float* __restrict__ b, float* __restrict__ out)
{
    const long row = (long)blockIdx.x * 4 + (threadIdx.x >> 6);
    const int lane = threadIdx.x & 63;
    const float4 v = *(const float4*)&pre[row * 256 + lane * 4];
    float s  = v.x + v.y + v.z + v.w;
    float s2 = v.x * v.x + v.y * v.y + v.z * v.z + v.w * v.w;
    #pragma unroll
    for (int off = 32; off > 0; off >>= 1) {
        s  += __shfl_xor(s, off);
        s2 += __shfl_xor(s2, off);
    }
    const float mu  = s * (1.f / 256.f);
    const float var = s2 * (1.f / 256.f) - mu * mu;
    const float inv = rsqrtf(var + 1e-5f);
    const float4 gg = *(const float4*)&g[lane * 4];
    const float4 bb = *(const float4*)&b[lane * 4];
    float4 o;
    o.x = (v.x - mu) * inv * gg.x + bb.x;
    o.y = (v.y - mu) * inv * gg.y + bb.y;
    o.z = (v.z - mu) * inv * gg.z + bb.z;
    o.w = (v.w - mu) * inv * gg.w + bb.w;
    *(float4*)&out[row * 256 + lane * 4] = o;
}

extern "C" void kernel_launch(void* const* d_in, const int* in_sizes, int n_in,
                              void* d_out, int out_size, void* d_ws, size_t ws_size,
                              hipStream_t stream)
{
    const float* x       = (const float*)d_in[0];
    const float* f_lin_W = (const float*)d_in[1];
    const float* f_lin_b = (const float*)d_in[2];
    const float* f_W_ih  = (const float*)d_in[3];
    const float* f_W_hh  = (const float*)d_in[4];
    const float* f_b_ih  = (const float*)d_in[5];
    const float* f_b_hh  = (const float*)d_in[6];
    const float* b_lin_W = (const float*)d_in[7];
    const float* b_lin_b = (const float*)d_in[8];
    const float* b_W_ih  = (const float*)d_in[9];
    const float* b_W_hh  = (const float*)d_in[10];
    const float* b_b_ih  = (const float*)d_in[11];
    const float* b_b_hh  = (const float*)d_in[12];
    const float* proj_W  = (const float*)d_in[13];
    const float* proj_b  = (const float*)d_in[14];
    const float* ln_g    = (const float*)d_in[15];
    const float* ln_bb   = (const float*)d_in[16];

    char* ws = (char*)d_ws;

    // ws: [Wp_f 384K | Wp_b 384K | bc_f 3K | bc_b 3K | (1MB) gi_f 192M | gi_b 192M | h1]
    // pre-LN fp32 (128MB) aliases gi_f region (gi dead by then).
    // h_out (f16, both dirs = 128MB) lives in d_out (fully overwritten by k_ln).
    const size_t BASE   = 1 << 20;
    const size_t GI_PER = (size_t)MTOT * 768 * 2;          // 201326592
    const size_t H1_OFF = BASE + 2 * GI_PER;
    const size_t H1_FULL = (size_t)MTOT * 512 * 2 * 2;     // both dirs
    int chunks = (ws_size >= H1_OFF + H1_FULL) ? 1
               : (ws_size >= H1_OFF + H1_FULL / 4) ? 4 : 8;
    const long MC = MTOT / chunks;

    _Float16* wpf = (_Float16*)ws;
    _Float16* wpb = (_Float16*)(ws + 393216);
    float*    bcf = (float*)(ws + 786432);
    float*    bcb = (float*)(ws + 786432 + 3072);
    _Float16* gif = (_Float16*)(ws + BASE);
    _Float16* gib = (_Float16*)(ws + BASE + GI_PER);
    float*    pre = (float*)(ws + BASE);
    _Float16* h1f = (_Float16*)(ws + H1_OFF);
    _Float16* h1b = h1f + MC * 512;

    _Float16* hof = (_Float16*)d_out;
    _Float16* hob = hof + MTOT * 256;

    k_prep_frag<<<96, 256, 0, stream>>>(f_W_hh, wpf);
    k_prep_frag<<<96, 256, 0, stream>>>(b_W_hh, wpb);
    k_prep_bias<<<3, 256, 0, stream>>>(f_b_ih, f_b_hh, bcf);
    k_prep_bias<<<3, 256, 0, stream>>>(b_b_ih, b_b_hh, bcb);

    for (int c = 0; c < chunks; ++c) {
        const long r0 = c * MC;
        k_gemm<0><<<dim3(MC / 64, 8),  256, 0, stream>>>(x + r0 * 256, nullptr, f_lin_W, f_lin_b, nullptr, h1f, 0L);
        k_gemm<0><<<dim3(MC / 64, 8),  256, 0, stream>>>(x + r0 * 256, nullptr, b_lin_W, b_lin_b, nullptr, h1b, 0L);
        // MODE 1 grid: x = N-blocks (12), y = M-blocks; scatter gets global rows via m_off
        k_gemm<1><<<dim3(12, MC / 64), 256, 0, stream>>>(h1f, nullptr, f_W_ih, bcf, nullptr, gif, r0);
        k_gemm<1><<<dim3(12, MC / 64), 256, 0, stream>>>(h1b, nullptr, b_W_ih, bcb, nullptr, gib, r0);
    }
    k_gru2<<<16, 512, 0, stream>>>(gif, gib, wpf, wpb, f_b_hh, b_b_hh, hof, hob);
    k_gemm<2><<<dim3(MTOT / 64, 4), 256, 0, stream>>>(hof, hob, proj_W, proj_b, x, pre, 0L);
    k_ln<<<MTOT / 4, 256, 0, stream>>>(pre, ln_g, ln_bb, (float*)d_out);
}

// Round 7
// 2898.124 us; speedup vs baseline: 1.1358x; 1.1358x over previous
//
#include <hip/hip_runtime.h>
#include <cmath>

// BiDirectionalSpatialMamba: lin+GELU -> GRU(fwd & bwd over P) -> proj+residual -> LN
// B=8 T=16 P=1024 H=256, D_INNER=512, 3H=768. M = B*T*P = 131072 rows.

typedef _Float16 h8  __attribute__((ext_vector_type(8)));
typedef _Float16 h2v __attribute__((ext_vector_type(2)));
typedef float    f32x4 __attribute__((ext_vector_type(4)));

#define MTOT 131072L
#define PSEQ 1024

__device__ __forceinline__ float fast_sigmoid(float x) {
    float e = __builtin_amdgcn_exp2f(-1.44269504089f * x);
    return __builtin_amdgcn_rcpf(1.f + e);
}
__device__ __forceinline__ float fast_tanh(float x) {
    float e = __builtin_amdgcn_exp2f(-2.88539008178f * x);
    return (1.f - e) * __builtin_amdgcn_rcpf(1.f + e);
}

// ---------------- GEMM: C[M x N] = A[M x K] @ B[K x N] + bias, f16 MFMA ----------
// MODE 0: A fp32 (x),   K=256 N=512, epilogue GELU(exact) -> f16 (h1)
// MODE 1: A f16 (h1),   K=512 N=768, epilogue +bias -> f16 gi, GRU-permuted layout
//         (scatter uses GLOBAL row = chunk-local row + m_off)
// MODE 2: A cat f16,    K=512 N=256, epilogue +b +x -> f32 (pre-LN)
template <int MODE>
__global__ __launch_bounds__(256) void k_gemm(
    const void* __restrict__ Aa_, const void* __restrict__ Ab_,
    const float* __restrict__ B, const float* __restrict__ bias,
    const float* __restrict__ xres, void* __restrict__ out_, long m_off)
{
    constexpr int K = (MODE == 0) ? 256 : 512;
    constexpr int N = (MODE == 0) ? 512 : (MODE == 1 ? 768 : 256);

    __shared__ __align__(16) _Float16 Al[64][40];  // [m][k], pad 32->40 (bank spread)
    __shared__ __align__(16) _Float16 Bl[64][40];  // [n][k]

    const int tid  = threadIdx.x;
    const int lane = tid & 63;
    const int wave = tid >> 6;
    const int wm = wave >> 1, wn = wave & 1;
    // MODE 1: x = N-blocks, y = M-blocks
    const long bm0 = (long)(MODE == 1 ? blockIdx.y : blockIdx.x) * 64;
    const int  bn0 = (MODE == 1 ? blockIdx.x : blockIdx.y) * 64;

    const int sm  = tid >> 2;          // A staging: row
    const int ska = (tid & 3) * 8;     // A staging: k offset
    const int sn  = tid & 63;          // B staging: col
    const int skb = (tid >> 6) * 8;    // B staging: k offset

    f32x4 acc[2][2] = {};

    for (int kt = 0; kt < K / 32; ++kt) {
        h8 av;
        if constexpr (MODE == 0) {
            const float* ap = (const float*)Aa_ + (bm0 + sm) * 256 + kt * 32 + ska;
            #pragma unroll
            for (int i = 0; i < 8; ++i) av[i] = (_Float16)ap[i];
        } else if constexpr (MODE == 1) {
            av = *(const h8*)((const _Float16*)Aa_ + (bm0 + sm) * 512 + kt * 32 + ska);
        } else {
            const _Float16* src = (kt < 8) ? (const _Float16*)Aa_ : (const _Float16*)Ab_;
            av = *(const h8*)(src + (bm0 + sm) * 256 + (kt & 7) * 32 + ska);
        }
        *(h8*)&Al[sm][ska] = av;

        h8 bv;
        #pragma unroll
        for (int i = 0; i < 8; ++i)
            bv[i] = (_Float16)B[(long)(kt * 32 + skb + i) * N + bn0 + sn];
        *(h8*)&Bl[sn][skb] = bv;

        __syncthreads();

        const int fr = lane & 15, fg = lane >> 4;
        h8 a0 = *(const h8*)&Al[wm * 32 +      fr][fg * 8];
        h8 a1 = *(const h8*)&Al[wm * 32 + 16 + fr][fg * 8];
        h8 b0 = *(const h8*)&Bl[wn * 32 +      fr][fg * 8];
        h8 b1 = *(const h8*)&Bl[wn * 32 + 16 + fr][fg * 8];
        acc[0][0] = __builtin_amdgcn_mfma_f32_16x16x32_f16(a0, b0, acc[0][0], 0, 0, 0);
        acc[0][1] = __builtin_amdgcn_mfma_f32_16x16x32_f16(a0, b1, acc[0][1], 0, 0, 0);
        acc[1][0] = __builtin_amdgcn_mfma_f32_16x16x32_f16(a1, b0, acc[1][0], 0, 0, 0);
        acc[1][1] = __builtin_amdgcn_mfma_f32_16x16x32_f16(a1, b1, acc[1][1], 0, 0, 0);

        __syncthreads();
    }

    const int fr = lane & 15, fg = lane >> 4;
    #pragma unroll
    for (int fm = 0; fm < 2; ++fm)
    #pragma unroll
    for (int fn = 0; fn < 2; ++fn)
    #pragma unroll
    for (int r = 0; r < 4; ++r) {
        long row = bm0 + wm * 32 + fm * 16 + fg * 4 + r;
        int  col = bn0 + wn * 32 + fn * 16 + fr;
        float v = acc[fm][fn][r] + bias[col];
        if constexpr (MODE == 0) {
            v = 0.5f * v * (1.0f + erff(v * 0.70710678118654752f));
            ((_Float16*)out_)[row * (long)N + col] = (_Float16)v;
        } else if constexpr (MODE == 1) {
            // scatter to GRU-permuted gi layout (bijective), GLOBAL rows:
            // [blk][p][g][thread(512)][e(8)] f16
            long grow = row + m_off;
            int seq = (int)(grow >> 10), p = (int)(grow & 1023);
            int blk = seq >> 4, srow = seq & 15;
            int g = col >> 8, ci = col & 255;
            int wv = ci >> 5, tp = (ci >> 4) & 1;
            int ln = (ci & 15) | ((srow >> 2) << 4);
            int e = tp * 4 + (srow & 3);
            long oidx = (((long)(blk * 1024 + p) * 3 + g) * 512 + (wv * 64 + ln)) * 8 + e;
            ((_Float16*)out_)[oidx] = (_Float16)v;
        } else {
            v += xres[row * 256 + col];
            ((float*)out_)[row * 256 + col] = v;
        }
    }
}

// ---------------- prep: W_hh fp32 [256][768] -> MFMA B-fragment layout f16 --------
__global__ __launch_bounds__(256) void k_prep_frag(
    const float* __restrict__ Whh, _Float16* __restrict__ Wp)
{
    const int t = blockIdx.x * 256 + threadIdx.x;   // < 24576
    const int l = t & 63, f = t >> 6;               // f < 384
    const int kt = f & 7;
    const int q  = f >> 3;          // < 48
    const int tp = q & 1;
    const int q2 = q >> 1;          // < 24
    const int g  = q2 % 3, w = q2 / 3;
    const int col = g * 256 + w * 32 + tp * 16 + (l & 15);
    const int k0  = kt * 32 + (l >> 4) * 8;
    h8 v;
    #pragma unroll
    for (int i = 0; i < 8; ++i)
        v[i] = (_Float16)Whh[(long)(k0 + i) * 768 + col];
    ((h8*)Wp)[t] = v;
}

// bc[col] = b_ih[col] + (col<512 ? b_hh[col] : 0)  (n-gate b_hh applied inside GRU)
__global__ __launch_bounds__(256) void k_prep_bias(
    const float* __restrict__ bih, const float* __restrict__ bhh, float* __restrict__ bc)
{
    const int c = blockIdx.x * 256 + threadIdx.x;   // < 768
    bc[c] = bih[c] + (c < 512 ? bhh[c] : 0.f);
}

// ---------------- GRU recurrence v4: MFMA, 16 blocks x 512 threads ----------------
// vs v3 (round 6, 4580 cyc/step vs 1862 MFMA-issue floor):
//  (1) gi prefetched ONE STEP AHEAD (register dbuf) -> HBM latency hidden under the
//      ~1900-cyc MFMA phase instead of stalling post-MFMA (round-6 counter gap (a)).
//  (2) gate phase split: r,z MFMA chains -> sigmoids -> n-gate chain; the sigmoid
//      VALU ops interleave with the 16 n-MFMAs (separate pipes, no deps).
// Budget: ~116 arch + 128 AGPR (bfrz) = 244/256 at 2 waves/SIMD; no spill.
__global__ __launch_bounds__(512, 2) void k_gru2(
    const _Float16* __restrict__ gpf, const _Float16* __restrict__ gpb,
    const _Float16* __restrict__ Wpf, const _Float16* __restrict__ Wpb,
    const float* __restrict__ bhhf, const float* __restrict__ bhhb,
    _Float16* __restrict__ hof, _Float16* __restrict__ hob)
{
    const int b = blockIdx.x;        // 16
    const int dir = b & 1;
    const int blk = b >> 1;          // seq-group [0,8)
    const int t = threadIdx.x;       // 512
    const int w = t >> 6, l = t & 63;
    const int lr = l & 15, lq = l >> 4;

    const _Float16* gp  = dir ? gpb : gpf;
    const _Float16* Wp  = dir ? Wpb : Wpf;
    const float*    bhh = dir ? bhhb : bhhf;
    _Float16*       hoo = dir ? hob : hof;

    __shared__ __align__(16) h8 wn_lds[8192];            // n-gate W frags [w][tp][kt][l] 128KB
    __shared__ __align__(16) _Float16 hbuf[2][16][264];  // dbuf h, pad 256->264

    // r,z B-fragments resident (AGPR); n-gate staged to LDS
    h8 bfrz[2][2][8];
    {
        const h8* src = (const h8*)Wp + (long)w * 48 * 64 + l;
        #pragma unroll
        for (int g = 0; g < 2; ++g)
        #pragma unroll
        for (int tp = 0; tp < 2; ++tp)
        #pragma unroll
        for (int kt = 0; kt < 8; ++kt)
            bfrz[g][tp][kt] = src[((g * 2 + tp) * 8 + kt) * 64];
        #pragma unroll
        for (int tp = 0; tp < 2; ++tp)
        #pragma unroll
        for (int kt = 0; kt < 8; ++kt)
            wn_lds[((w * 2 + tp) * 8 + kt) * 64 + l] = src[((4 + tp) * 8 + kt) * 64];
    }
    const int col0 = w * 32 + lr;                  // thread's h-col (tp=0)
    const float bn0 = bhh[512 + col0];
    const float bn1 = bhh[512 + col0 + 16];

    for (int i = t; i < 2 * 16 * 264; i += 512) ((_Float16*)hbuf)[i] = (_Float16)0.f;
    __syncthreads();

    const int d = dir ? -1 : 1;
    int p = dir ? (PSEQ - 1) : 0;
    int cur = 0;
    const long tbase = (long)t * 8;
    const long bbase = (long)blk * 1024;
    float hold[2][4] = {};

    // prologue: gi for the first position
    h8 gv0 = *(const h8*)(gp + ((bbase + p) * 3 + 0) * 4096 + tbase);
    h8 gv1 = *(const h8*)(gp + ((bbase + p) * 3 + 1) * 4096 + tbase);
    h8 gv2 = *(const h8*)(gp + ((bbase + p) * 3 + 2) * 4096 + tbase);

    for (int step = 0; step < PSEQ; ++step) {
        // prefetch NEXT step's gi; latency hidden under this step's MFMA phase
        int pn = p + d;
        pn = pn < 0 ? 0 : (pn > PSEQ - 1 ? PSEQ - 1 : pn);
        h8 nv0 = *(const h8*)(gp + ((bbase + pn) * 3 + 0) * 4096 + tbase);
        h8 nv1 = *(const h8*)(gp + ((bbase + pn) * 3 + 1) * 4096 + tbase);
        h8 nv2 = *(const h8*)(gp + ((bbase + pn) * 3 + 2) * 4096 + tbase);

        // A-fragments from LDS h
        h8 af[8];
        #pragma unroll
        for (int kt = 0; kt < 8; ++kt)
            af[kt] = *(const h8*)&hbuf[cur][lr][kt * 32 + lq * 8];

        // ---- phase 1: r,z gate chains ----
        f32x4 accr[2] = {}, accz[2] = {};
        #pragma unroll
        for (int kt = 0; kt < 8; ++kt) {
            #pragma unroll
            for (int tp = 0; tp < 2; ++tp) {
                accr[tp] = __builtin_amdgcn_mfma_f32_16x16x32_f16(af[kt], bfrz[0][tp][kt], accr[tp], 0, 0, 0);
                accz[tp] = __builtin_amdgcn_mfma_f32_16x16x32_f16(af[kt], bfrz[1][tp][kt], accz[tp], 0, 0, 0);
            }
        }

        // ---- sigmoids (scheduler interleaves these with phase-2 MFMA issue) ----
        float rr[2][4], zz[2][4];
        #pragma unroll
        for (int tp = 0; tp < 2; ++tp)
        #pragma unroll
        for (int r = 0; r < 4; ++r) {
            const int e = tp * 4 + r;
            rr[tp][r] = fast_sigmoid(accr[tp][r] + (float)gv0[e]);
            zz[tp][r] = fast_sigmoid(accz[tp][r] + (float)gv1[e]);
        }

        // ---- phase 2: n gate chain (weights from LDS) ----
        f32x4 accn[2] = {};
        #pragma unroll
        for (int kt = 0; kt < 8; ++kt) {
            h8 bfn0 = wn_lds[((w * 2 + 0) * 8 + kt) * 64 + l];
            h8 bfn1 = wn_lds[((w * 2 + 1) * 8 + kt) * 64 + l];
            accn[0] = __builtin_amdgcn_mfma_f32_16x16x32_f16(af[kt], bfn0, accn[0], 0, 0, 0);
            accn[1] = __builtin_amdgcn_mfma_f32_16x16x32_f16(af[kt], bfn1, accn[1], 0, 0, 0);
        }

        // ---- finish: tanh, h update, stores ----
        #pragma unroll
        for (int tp = 0; tp < 2; ++tp) {
            const int col = col0 + tp * 16;
            const float bn = tp ? bn1 : bn0;
            #pragma unroll
            for (int r = 0; r < 4; ++r) {
                const int e = tp * 4 + r;
                float nh = accn[tp][r] + bn;
                float nn = fast_tanh((float)gv2[e] + rr[tp][r] * nh);
                float h  = fmaf(zz[tp][r], hold[tp][r] - nn, nn);
                hold[tp][r] = h;
                _Float16 hf = (_Float16)h;
                const int row = lq * 4 + r;
                hbuf[cur ^ 1][row][col] = hf;
                hoo[((long)(blk * 16 + row) * PSEQ + p) * 256 + col] = hf;
            }
        }
        __syncthreads();   // h[cur^1] complete before next step's A-reads

        cur ^= 1; p += d;
        gv0 = nv0; gv1 = nv1; gv2 = nv2;
    }
}

// ---------------- LayerNorm over H=256, wave per row ------------------------------
__global__ __launch_bounds__(256) void k_ln(
    const float* __restrict__ pre, const float* __restrict__ g,
    const float* __restrict__ b, float* __restrict__ out)
{
    const long row = (long)blockIdx.x * 4 + (threadIdx.x >> 6);
    const int lane = threadIdx.x & 63;
    const float4 v = *(const float4*)&pre[row * 256 + lane * 4];
    float s  = v.x + v.y + v.z + v.w;
    float s2 = v.x * v.x + v.y * v.y + v.z * v.z + v.w * v.w;
    #pragma unroll
    for (int off = 32; off > 0; off >>= 1) {
        s  += __shfl_xor(s, off);
        s2 += __shfl_xor(s2, off);
    }
    const float mu  = s * (1.f / 256.f);
    const float var = s2 * (1.f / 256.f) - mu * mu;
    const float inv = rsqrtf(var + 1e-5f);
    const float4 gg = *(const float4*)&g[lane * 4];
    const float4 bb = *(const float4*)&b[lane * 4];
    float4 o;
    o.x = (v.x - mu) * inv * gg.x + bb.x;
    o.y = (v.y - mu) * inv * gg.y + bb.y;
    o.z = (v.z - mu) * inv * gg.z + bb.z;
    o.w = (v.w - mu) * inv * gg.w + bb.w;
    *(float4*)&out[row * 256 + lane * 4] = o;
}

extern "C" void kernel_launch(void* const* d_in, const int* in_sizes, int n_in,
                              void* d_out, int out_size, void* d_ws, size_t ws_size,
                              hipStream_t stream)
{
    const float* x       = (const float*)d_in[0];
    const float* f_lin_W = (const float*)d_in[1];
    const float* f_lin_b = (const float*)d_in[2];
    const float* f_W_ih  = (const float*)d_in[3];
    const float* f_W_hh  = (const float*)d_in[4];
    const float* f_b_ih  = (const float*)d_in[5];
    const float* f_b_hh  = (const float*)d_in[6];
    const float* b_lin_W = (const float*)d_in[7];
    const float* b_lin_b = (const float*)d_in[8];
    const float* b_W_ih  = (const float*)d_in[9];
    const float* b_W_hh  = (const float*)d_in[10];
    const float* b_b_ih  = (const float*)d_in[11];
    const float* b_b_hh  = (const float*)d_in[12];
    const float* proj_W  = (const float*)d_in[13];
    const float* proj_b  = (const float*)d_in[14];
    const float* ln_g    = (const float*)d_in[15];
    const float* ln_bb   = (const float*)d_in[16];

    char* ws = (char*)d_ws;

    // ws: [Wp_f 384K | Wp_b 384K | bc_f 3K | bc_b 3K | (1MB) gi_f 192M | gi_b 192M | h1]
    // pre-LN fp32 (128MB) aliases gi_f region (gi dead by then).
    // h_out (f16, both dirs = 128MB) lives in d_out (fully overwritten by k_ln).
    const size_t BASE   = 1 << 20;
    const size_t GI_PER = (size_t)MTOT * 768 * 2;          // 201326592
    const size_t H1_OFF = BASE + 2 * GI_PER;
    const size_t H1_FULL = (size_t)MTOT * 512 * 2 * 2;     // both dirs
    int chunks = (ws_size >= H1_OFF + H1_FULL) ? 1
               : (ws_size >= H1_OFF + H1_FULL / 4) ? 4 : 8;
    const long MC = MTOT / chunks;

    _Float16* wpf = (_Float16*)ws;
    _Float16* wpb = (_Float16*)(ws + 393216);
    float*    bcf = (float*)(ws + 786432);
    float*    bcb = (float*)(ws + 786432 + 3072);
    _Float16* gif = (_Float16*)(ws + BASE);
    _Float16* gib = (_Float16*)(ws + BASE + GI_PER);
    float*    pre = (float*)(ws + BASE);
    _Float16* h1f = (_Float16*)(ws + H1_OFF);
    _Float16* h1b = h1f + MC * 512;

    _Float16* hof = (_Float16*)d_out;
    _Float16* hob = hof + MTOT * 256;

    k_prep_frag<<<96, 256, 0, stream>>>(f_W_hh, wpf);
    k_prep_frag<<<96, 256, 0, stream>>>(b_W_hh, wpb);
    k_prep_bias<<<3, 256, 0, stream>>>(f_b_ih, f_b_hh, bcf);
    k_prep_bias<<<3, 256, 0, stream>>>(b_b_ih, b_b_hh, bcb);

    for (int c = 0; c < chunks; ++c) {
        const long r0 = c * MC;
        k_gemm<0><<<dim3(MC / 64, 8),  256, 0, stream>>>(x + r0 * 256, nullptr, f_lin_W, f_lin_b, nullptr, h1f, 0L);
        k_gemm<0><<<dim3(MC / 64, 8),  256, 0, stream>>>(x + r0 * 256, nullptr, b_lin_W, b_lin_b, nullptr, h1b, 0L);
        // MODE 1 grid: x = N-blocks (12), y = M-blocks; scatter gets global rows via m_off
        k_gemm<1><<<dim3(12, MC / 64), 256, 0, stream>>>(h1f, nullptr, f_W_ih, bcf, nullptr, gif, r0);
        k_gemm<1><<<dim3(12, MC / 64), 256, 0, stream>>>(h1b, nullptr, b_W_ih, bcb, nullptr, gib, r0);
    }
    k_gru2<<<16, 512, 0, stream>>>(gif, gib, wpf, wpb, f_b_hh, b_b_hh, hof, hob);
    k_gemm<2><<<dim3(MTOT / 64, 4), 256, 0, stream>>>(hof, hob, proj_W, proj_b, x, pre, 0L);
    k_ln<<<MTOT / 4, 256, 0, stream>>>(pre, ln_g, ln_bb, (float*)d_out);
}

// Round 8
// 2528.305 us; speedup vs baseline: 1.3019x; 1.1463x over previous
//
#include <hip/hip_runtime.h>
#include <cmath>

// BiDirectionalSpatialMamba: lin+GELU -> GRU(fwd & bwd over P) -> proj+residual -> LN
// B=8 T=16 P=1024 H=256, D_INNER=512, 3H=768. M = B*T*P = 131072 rows.

typedef _Float16 h8  __attribute__((ext_vector_type(8)));
typedef float    f32x4 __attribute__((ext_vector_type(4)));

#define MTOT 131072L
#define PSEQ 1024

__device__ __forceinline__ float fast_sigmoid(float x) {
    float e = __builtin_amdgcn_exp2f(-1.44269504089f * x);
    return __builtin_amdgcn_rcpf(1.f + e);
}
__device__ __forceinline__ float fast_tanh(float x) {
    float e = __builtin_amdgcn_exp2f(-2.88539008178f * x);
    return (1.f - e) * __builtin_amdgcn_rcpf(1.f + e);
}

// async global->LDS, 16B per lane; dest = wave-uniform base + lane*16
__device__ __forceinline__ void gl_lds16(const void* g, void* lds_wave_base, int lane) {
#if defined(__has_builtin) && __has_builtin(__builtin_amdgcn_global_load_lds)
    __builtin_amdgcn_global_load_lds(
        (const __attribute__((address_space(1))) void*)g,
        (__attribute__((address_space(3))) void*)lds_wave_base, 16, 0, 0);
#else
    *((h8*)lds_wave_base + lane) = *(const h8*)g;
#endif
}

// ---------------- unified m97-style GEMM: 128x128 tile, 4 waves, 4x4 acc --------
// C[M x N] = A[M x K] @ Bt^T + bias   (Bt is f16 [N][K], pre-transposed weights)
// MODE 0: A = x fp32 [M][256] (reg-staged cvt), K=256 N=1024, GELU -> h1cat f16 [M][1024]
// MODE 1: A = h1cat f16 (lda 1024, fwd/bwd via base ptr), K=512 N=768,
//         epilogue -> gi permuted scatter (GLOBAL row = row + m_off)
// MODE 2: A = cat(hof,hob) f16 (kt<8 -> hof), K=512 N=256, +bias +x -> f32 pre-LN
template <int MODE>
__global__ __launch_bounds__(256) void k_gemm2(
    const void* __restrict__ Aa_, const void* __restrict__ Ab_,
    const _Float16* __restrict__ Bt, const float* __restrict__ bias,
    const float* __restrict__ xres, void* __restrict__ out_, long m_off)
{
    constexpr int K   = (MODE == 0) ? 256 : 512;
    constexpr int NKT = K / 32;

    __shared__ __align__(16) _Float16 Al[128 * 32];  // [row][k] linear, 64B rows
    __shared__ __align__(16) _Float16 Bl[128 * 32];  // [col][k] linear

    const int t  = threadIdx.x;
    const int wv = t >> 6, l = t & 63;
    const int fr = l & 15, fg = l >> 4;
    const int wm = wv >> 1, wn = wv & 1;
    const long bm0 = (long)blockIdx.x * 128;
    const int  bn0 = blockIdx.y * 128;
    const int sr = t >> 2, sc = t & 3;   // staging: row-in-round, 16B chunk

    f32x4 acc[4][4] = {};

    for (int kt = 0; kt < NKT; ++kt) {
        // ---- B staging (f16 [N][K]) via global_load_lds ----
        #pragma unroll
        for (int q = 0; q < 2; ++q) {
            const int r = q * 64 + sr;
            const _Float16* g = Bt + (long)(bn0 + r) * K + kt * 32 + sc * 8;
            gl_lds16(g, (char*)Bl + q * 4096 + wv * 1024, l);
        }
        // ---- A staging ----
        if constexpr (MODE == 0) {
            #pragma unroll
            for (int q = 0; q < 2; ++q) {
                const int r = q * 64 + sr;
                const float* xs = (const float*)Aa_ + (bm0 + r) * 256 + kt * 32 + sc * 8;
                float4 v0 = *(const float4*)xs;
                float4 v1 = *(const float4*)(xs + 4);
                h8 hv;
                hv[0] = (_Float16)v0.x; hv[1] = (_Float16)v0.y;
                hv[2] = (_Float16)v0.z; hv[3] = (_Float16)v0.w;
                hv[4] = (_Float16)v1.x; hv[5] = (_Float16)v1.y;
                hv[6] = (_Float16)v1.z; hv[7] = (_Float16)v1.w;
                *(h8*)((char*)Al + r * 64 + sc * 16) = hv;
            }
        } else if constexpr (MODE == 1) {
            #pragma unroll
            for (int q = 0; q < 2; ++q) {
                const int r = q * 64 + sr;
                const _Float16* g = (const _Float16*)Aa_ + (bm0 + r) * 1024 + kt * 32 + sc * 8;
                gl_lds16(g, (char*)Al + q * 4096 + wv * 1024, l);
            }
        } else {
            const _Float16* src = (kt < 8) ? (const _Float16*)Aa_ : (const _Float16*)Ab_;
            #pragma unroll
            for (int q = 0; q < 2; ++q) {
                const int r = q * 64 + sr;
                const _Float16* g = src + (bm0 + r) * 256 + (kt & 7) * 32 + sc * 8;
                gl_lds16(g, (char*)Al + q * 4096 + wv * 1024, l);
            }
        }
        __syncthreads();

        h8 af[4], bf[4];
        #pragma unroll
        for (int fm = 0; fm < 4; ++fm)
            af[fm] = *(const h8*)((const char*)Al + (wm * 64 + fm * 16 + fr) * 64 + fg * 16);
        #pragma unroll
        for (int fn = 0; fn < 4; ++fn)
            bf[fn] = *(const h8*)((const char*)Bl + (wn * 64 + fn * 16 + fr) * 64 + fg * 16);
        #pragma unroll
        for (int fm = 0; fm < 4; ++fm)
        #pragma unroll
        for (int fn = 0; fn < 4; ++fn)
            acc[fm][fn] = __builtin_amdgcn_mfma_f32_16x16x32_f16(af[fm], bf[fn], acc[fm][fn], 0, 0, 0);
        __syncthreads();
    }

    #pragma unroll
    for (int fm = 0; fm < 4; ++fm)
    #pragma unroll
    for (int fn = 0; fn < 4; ++fn)
    #pragma unroll
    for (int r = 0; r < 4; ++r) {
        long row = bm0 + wm * 64 + fm * 16 + fg * 4 + r;
        int  col = bn0 + wn * 64 + fn * 16 + fr;
        float v = acc[fm][fn][r] + bias[col];
        if constexpr (MODE == 0) {
            v = 0.5f * v * (1.0f + erff(v * 0.70710678118654752f));
            ((_Float16*)out_)[row * 1024 + col] = (_Float16)v;
        } else if constexpr (MODE == 1) {
            // permuted gi scatter (bijective), GLOBAL rows: [blk][p][g][thread(512)][e(8)]
            long grow = row + m_off;
            int seq = (int)(grow >> 10), p = (int)(grow & 1023);
            int blk = seq >> 4, srow = seq & 15;
            int g = col >> 8, ci = col & 255;
            int wvx = ci >> 5, tp = (ci >> 4) & 1;
            int ln = (ci & 15) | ((srow >> 2) << 4);
            int e = tp * 4 + (srow & 3);
            long oidx = (((long)(blk * 1024 + p) * 3 + g) * 512 + (wvx * 64 + ln)) * 8 + e;
            ((_Float16*)out_)[oidx] = (_Float16)v;
        } else {
            v += xres[row * 256 + col];
            ((float*)out_)[row * 256 + col] = v;
        }
    }
}

// ---------------- prep: transpose-convert fp32 [K][N] -> f16 [N][K] --------------
__global__ __launch_bounds__(256) void k_prep_wt(
    const float* __restrict__ src, _Float16* __restrict__ dst, int Kd, int Nd)
{
    const int i = blockIdx.x * 256 + threadIdx.x;
    if (i >= Kd * Nd) return;
    const int n = i / Kd, k = i % Kd;
    dst[i] = (_Float16)src[(long)k * Nd + n];
}

// lin bias concat [1024]
__global__ __launch_bounds__(256) void k_prep_lb(
    const float* __restrict__ fb, const float* __restrict__ bb, float* __restrict__ dst)
{
    const int i = blockIdx.x * 256 + threadIdx.x;
    dst[i] = (i < 512) ? fb[i] : bb[i - 512];
}

// ---------------- prep: W_hh fp32 [256][768] -> MFMA B-fragment layout f16 --------
__global__ __launch_bounds__(256) void k_prep_frag(
    const float* __restrict__ Whh, _Float16* __restrict__ Wp)
{
    const int t = blockIdx.x * 256 + threadIdx.x;   // < 24576
    const int l = t & 63, f = t >> 6;               // f < 384
    const int kt = f & 7;
    const int q  = f >> 3;          // < 48
    const int tp = q & 1;
    const int q2 = q >> 1;          // < 24
    const int g  = q2 % 3, w = q2 / 3;
    const int col = g * 256 + w * 32 + tp * 16 + (l & 15);
    const int k0  = kt * 32 + (l >> 4) * 8;
    h8 v;
    #pragma unroll
    for (int i = 0; i < 8; ++i)
        v[i] = (_Float16)Whh[(long)(k0 + i) * 768 + col];
    ((h8*)Wp)[t] = v;
}

// bc[col] = b_ih[col] + (col<512 ? b_hh[col] : 0)  (n-gate b_hh applied inside GRU)
__global__ __launch_bounds__(256) void k_prep_bias(
    const float* __restrict__ bih, const float* __restrict__ bhh, float* __restrict__ bc)
{
    const int c = blockIdx.x * 256 + threadIdx.x;   // < 768
    bc[c] = bih[c] + (c < 512 ? bhh[c] : 0.f);
}

// ---------------- GRU recurrence v4 (unchanged from round 7) ---------------------
__global__ __launch_bounds__(512, 2) void k_gru2(
    const _Float16* __restrict__ gpf, const _Float16* __restrict__ gpb,
    const _Float16* __restrict__ Wpf, const _Float16* __restrict__ Wpb,
    const float* __restrict__ bhhf, const float* __restrict__ bhhb,
    _Float16* __restrict__ hof, _Float16* __restrict__ hob)
{
    const int b = blockIdx.x;        // 16
    const int dir = b & 1;
    const int blk = b >> 1;          // seq-group [0,8)
    const int t = threadIdx.x;       // 512
    const int w = t >> 6, l = t & 63;
    const int lr = l & 15, lq = l >> 4;

    const _Float16* gp  = dir ? gpb : gpf;
    const _Float16* Wp  = dir ? Wpb : Wpf;
    const float*    bhh = dir ? bhhb : bhhf;
    _Float16*       hoo = dir ? hob : hof;

    __shared__ __align__(16) h8 wn_lds[8192];            // n-gate W frags 128KB
    __shared__ __align__(16) _Float16 hbuf[2][16][264];  // dbuf h, pad 256->264

    h8 bfrz[2][2][8];
    {
        const h8* src = (const h8*)Wp + (long)w * 48 * 64 + l;
        #pragma unroll
        for (int g = 0; g < 2; ++g)
        #pragma unroll
        for (int tp = 0; tp < 2; ++tp)
        #pragma unroll
        for (int kt = 0; kt < 8; ++kt)
            bfrz[g][tp][kt] = src[((g * 2 + tp) * 8 + kt) * 64];
        #pragma unroll
        for (int tp = 0; tp < 2; ++tp)
        #pragma unroll
        for (int kt = 0; kt < 8; ++kt)
            wn_lds[((w * 2 + tp) * 8 + kt) * 64 + l] = src[((4 + tp) * 8 + kt) * 64];
    }
    const int col0 = w * 32 + lr;
    const float bn0 = bhh[512 + col0];
    const float bn1 = bhh[512 + col0 + 16];

    for (int i = t; i < 2 * 16 * 264; i += 512) ((_Float16*)hbuf)[i] = (_Float16)0.f;
    __syncthreads();

    const int d = dir ? -1 : 1;
    int p = dir ? (PSEQ - 1) : 0;
    int cur = 0;
    const long tbase = (long)t * 8;
    const long bbase = (long)blk * 1024;
    float hold[2][4] = {};

    h8 gv0 = *(const h8*)(gp + ((bbase + p) * 3 + 0) * 4096 + tbase);
    h8 gv1 = *(const h8*)(gp + ((bbase + p) * 3 + 1) * 4096 + tbase);
    h8 gv2 = *(const h8*)(gp + ((bbase + p) * 3 + 2) * 4096 + tbase);

    for (int step = 0; step < PSEQ; ++step) {
        int pn = p + d;
        pn = pn < 0 ? 0 : (pn > PSEQ - 1 ? PSEQ - 1 : pn);
        h8 nv0 = *(const h8*)(gp + ((bbase + pn) * 3 + 0) * 4096 + tbase);
        h8 nv1 = *(const h8*)(gp + ((bbase + pn) * 3 + 1) * 4096 + tbase);
        h8 nv2 = *(const h8*)(gp + ((bbase + pn) * 3 + 2) * 4096 + tbase);

        h8 af[8];
        #pragma unroll
        for (int kt = 0; kt < 8; ++kt)
            af[kt] = *(const h8*)&hbuf[cur][lr][kt * 32 + lq * 8];

        f32x4 accr[2] = {}, accz[2] = {};
        #pragma unroll
        for (int kt = 0; kt < 8; ++kt) {
            #pragma unroll
            for (int tp = 0; tp < 2; ++tp) {
                accr[tp] = __builtin_amdgcn_mfma_f32_16x16x32_f16(af[kt], bfrz[0][tp][kt], accr[tp], 0, 0, 0);
                accz[tp] = __builtin_amdgcn_mfma_f32_16x16x32_f16(af[kt], bfrz[1][tp][kt], accz[tp], 0, 0, 0);
            }
        }

        float rr[2][4], zz[2][4];
        #pragma unroll
        for (int tp = 0; tp < 2; ++tp)
        #pragma unroll
        for (int r = 0; r < 4; ++r) {
            const int e = tp * 4 + r;
            rr[tp][r] = fast_sigmoid(accr[tp][r] + (float)gv0[e]);
            zz[tp][r] = fast_sigmoid(accz[tp][r] + (float)gv1[e]);
        }

        f32x4 accn[2] = {};
        #pragma unroll
        for (int kt = 0; kt < 8; ++kt) {
            h8 bfn0 = wn_lds[((w * 2 + 0) * 8 + kt) * 64 + l];
            h8 bfn1 = wn_lds[((w * 2 + 1) * 8 + kt) * 64 + l];
            accn[0] = __builtin_amdgcn_mfma_f32_16x16x32_f16(af[kt], bfn0, accn[0], 0, 0, 0);
            accn[1] = __builtin_amdgcn_mfma_f32_16x16x32_f16(af[kt], bfn1, accn[1], 0, 0, 0);
        }

        #pragma unroll
        for (int tp = 0; tp < 2; ++tp) {
            const int col = col0 + tp * 16;
            const float bn = tp ? bn1 : bn0;
            #pragma unroll
            for (int r = 0; r < 4; ++r) {
                const int e = tp * 4 + r;
                float nh = accn[tp][r] + bn;
                float nn = fast_tanh((float)gv2[e] + rr[tp][r] * nh);
                float h  = fmaf(zz[tp][r], hold[tp][r] - nn, nn);
                hold[tp][r] = h;
                _Float16 hf = (_Float16)h;
                const int row = lq * 4 + r;
                hbuf[cur ^ 1][row][col] = hf;
                hoo[((long)(blk * 16 + row) * PSEQ + p) * 256 + col] = hf;
            }
        }
        __syncthreads();

        cur ^= 1; p += d;
        gv0 = nv0; gv1 = nv1; gv2 = nv2;
    }
}

// ---------------- LayerNorm over H=256, wave per row ------------------------------
__global__ __launch_bounds__(256) void k_ln(
    const float* __restrict__ pre, const float* __restrict__ g,
    const float* __restrict__ b, float* __restrict__ out)
{
    const long row = (long)blockIdx.x * 4 + (threadIdx.x >> 6);
    const int lane = threadIdx.x & 63;
    const float4 v = *(const float4*)&pre[row * 256 + lane * 4];
    float s  = v.x + v.y + v.z + v.w;
    float s2 = v.x * v.x + v.y * v.y + v.z * v.z + v.w * v.w;
    #pragma unroll
    for (int off = 32; off > 0; off >>= 1) {
        s  += __shfl_xor(s, off);
        s2 += __shfl_xor(s2, off);
    }
    const float mu  = s * (1.f / 256.f);
    const float var = s2 * (1.f / 256.f) - mu * mu;
    const float inv = rsqrtf(var + 1e-5f);
    const float4 gg = *(const float4*)&g[lane * 4];
    const float4 bb = *(const float4*)&b[lane * 4];
    float4 o;
    o.x = (v.x - mu) * inv * gg.x + bb.x;
    o.y = (v.y - mu) * inv * gg.y + bb.y;
    o.z = (v.z - mu) * inv * gg.z + bb.z;
    o.w = (v.w - mu) * inv * gg.w + bb.w;
    *(float4*)&out[row * 256 + lane * 4] = o;
}

extern "C" void kernel_launch(void* const* d_in, const int* in_sizes, int n_in,
                              void* d_out, int out_size, void* d_ws, size_t ws_size,
                              hipStream_t stream)
{
    const float* x       = (const float*)d_in[0];
    const float* f_lin_W = (const float*)d_in[1];
    const float* f_lin_b = (const float*)d_in[2];
    const float* f_W_ih  = (const float*)d_in[3];
    const float* f_W_hh  = (const float*)d_in[4];
    const float* f_b_ih  = (const float*)d_in[5];
    const float* f_b_hh  = (const float*)d_in[6];
    const float* b_lin_W = (const float*)d_in[7];
    const float* b_lin_b = (const float*)d_in[8];
    const float* b_W_ih  = (const float*)d_in[9];
    const float* b_W_hh  = (const float*)d_in[10];
    const float* b_b_ih  = (const float*)d_in[11];
    const float* b_b_hh  = (const float*)d_in[12];
    const float* proj_W  = (const float*)d_in[13];
    const float* proj_b  = (const float*)d_in[14];
    const float* ln_g    = (const float*)d_in[15];
    const float* ln_bb   = (const float*)d_in[16];

    char* ws = (char*)d_ws;

    // ws: [weights/bias preps < 4MB | gi_f 192M | gi_b 192M | h1cat chunk]
    // pre-LN fp32 (128MB) aliases gi_f (gi dead by MODE 2).
    // h_out f16 (both dirs, 128MB) lives in d_out (fully overwritten by k_ln).
    size_t o = 0;
    _Float16* wt_lin  = (_Float16*)(ws + o); o += 1024 * 256 * 2;   // 512K
    _Float16* wt_ihf  = (_Float16*)(ws + o); o += 768 * 512 * 2;    // 768K
    _Float16* wt_ihb  = (_Float16*)(ws + o); o += 768 * 512 * 2;
    _Float16* wt_proj = (_Float16*)(ws + o); o += 256 * 512 * 2;    // 256K
    float*    bl_lin  = (float*)(ws + o);    o += 1024 * 4;
    float*    bcf     = (float*)(ws + o);    o += 768 * 4;
    float*    bcb     = (float*)(ws + o);    o += 768 * 4;
    _Float16* wpf     = (_Float16*)(ws + o); o += 393216;
    _Float16* wpb     = (_Float16*)(ws + o); o += 393216;

    const size_t BASE   = 4u << 20;
    const size_t GI_PER = (size_t)MTOT * 768 * 2;          // 192MB
    const size_t GI_END = BASE + 2 * GI_PER;               // 388MB
    int chunks = 1;
    while (GI_END + (size_t)(MTOT / chunks) * 1024 * 2 > ws_size && chunks < 16)
        chunks <<= 1;
    const long MC = MTOT / chunks;

    _Float16* gif   = (_Float16*)(ws + BASE);
    _Float16* gib   = (_Float16*)(ws + BASE + GI_PER);
    float*    pre   = (float*)(ws + BASE);
    _Float16* h1cat = (_Float16*)(ws + GI_END);

    _Float16* hof = (_Float16*)d_out;
    _Float16* hob = hof + MTOT * 256;

    // ---- weight preps (one-time, tiny) ----
    k_prep_wt<<<512,  256, 0, stream>>>(f_lin_W, wt_lin,             256, 512);
    k_prep_wt<<<512,  256, 0, stream>>>(b_lin_W, wt_lin + 512 * 256, 256, 512);
    k_prep_wt<<<1536, 256, 0, stream>>>(f_W_ih,  wt_ihf,             512, 768);
    k_prep_wt<<<1536, 256, 0, stream>>>(b_W_ih,  wt_ihb,             512, 768);
    k_prep_wt<<<512,  256, 0, stream>>>(proj_W,  wt_proj,            512, 256);
    k_prep_lb<<<4,    256, 0, stream>>>(f_lin_b, b_lin_b, bl_lin);
    k_prep_bias<<<3,  256, 0, stream>>>(f_b_ih, f_b_hh, bcf);
    k_prep_bias<<<3,  256, 0, stream>>>(b_b_ih, b_b_hh, bcb);
    k_prep_frag<<<96, 256, 0, stream>>>(f_W_hh, wpf);
    k_prep_frag<<<96, 256, 0, stream>>>(b_W_hh, wpb);

    // ---- position-wise front GEMMs, M-chunked ----
    for (int c = 0; c < chunks; ++c) {
        const long r0 = c * MC;
        k_gemm2<0><<<dim3(MC / 128, 8), 256, 0, stream>>>(
            x + r0 * 256, nullptr, wt_lin, bl_lin, nullptr, h1cat, 0L);
        k_gemm2<1><<<dim3(MC / 128, 6), 256, 0, stream>>>(
            h1cat, nullptr, wt_ihf, bcf, nullptr, gif, r0);
        k_gemm2<1><<<dim3(MC / 128, 6), 256, 0, stream>>>(
            h1cat + 512, nullptr, wt_ihb, bcb, nullptr, gib, r0);
    }
    k_gru2<<<16, 512, 0, stream>>>(gif, gib, wpf, wpb, f_b_hh, b_b_hh, hof, hob);
    k_gemm2<2><<<dim3(MTOT / 128, 2), 256, 0, stream>>>(
        hof, hob, wt_proj, proj_b, x, pre, 0L);
    k_ln<<<MTOT / 4, 256, 0, stream>>>(pre, ln_g, ln_bb, (float*)d_out);
}

// Round 9
// 2401.882 us; speedup vs baseline: 1.3705x; 1.0526x over previous
//
#include <hip/hip_runtime.h>
#include <cmath>

// BiDirectionalSpatialMamba: lin+GELU -> GRU(fwd & bwd over P) -> proj+residual -> LN
// B=8 T=16 P=1024 H=256, D_INNER=512, 3H=768. M = B*T*P = 131072 rows.

typedef _Float16 h8  __attribute__((ext_vector_type(8)));
typedef float    f32x4 __attribute__((ext_vector_type(4)));

#define MTOT 131072L
#define PSEQ 1024

__device__ __forceinline__ float fast_sigmoid(float x) {
    float e = __builtin_amdgcn_exp2f(-1.44269504089f * x);
    return __builtin_amdgcn_rcpf(1.f + e);
}
__device__ __forceinline__ float fast_tanh(float x) {
    float e = __builtin_amdgcn_exp2f(-2.88539008178f * x);
    return (1.f - e) * __builtin_amdgcn_rcpf(1.f + e);
}

// async global->LDS, 16B per lane; dest = wave-uniform base + lane*16
__device__ __forceinline__ void gl_lds16(const void* g, void* lds_wave_base, int lane) {
#if defined(__has_builtin) && __has_builtin(__builtin_amdgcn_global_load_lds)
    __builtin_amdgcn_global_load_lds(
        (const __attribute__((address_space(1))) void*)g,
        (__attribute__((address_space(3))) void*)lds_wave_base, 16, 0, 0);
#else
    *((h8*)lds_wave_base + lane) = *(const h8*)g;
#endif
}

// ---------------- unified m97-style GEMM: 128x128 tile, 4 waves, 4x4 acc --------
// C[M x N] = A[M x K] @ Bt^T + bias   (Bt is f16 [N][K], pre-transposed weights)
// MODE 0: A = x fp32 [M][256], K=256 N=1024, GELU -> h1cat f16 [M][1024]
//         epilogue via LDS stage -> 16B coalesced stores (kills 2x write amp)
// MODE 1: A = h1cat f16 (lda 1024), K=512 N=768. M-tile = 4 seqs x 32 p so each
//         gi slot's 8 e-bytes (2 cols x 4 seqs) are in-tile; epilogue stages C in
//         LDS, gathers, emits DENSE 16B gi stores (kills the 8x write amp).
// MODE 2: A = cat(hof,hob) f16 (kt<8 -> hof), K=512 N=256, +bias +x -> f32 pre-LN
template <int MODE>
__global__ __launch_bounds__(256) void k_gemm2(
    const void* __restrict__ Aa_, const void* __restrict__ Ab_,
    const _Float16* __restrict__ Bt, const float* __restrict__ bias,
    const float* __restrict__ xres, void* __restrict__ out_, long m_off)
{
    constexpr int K   = (MODE == 0) ? 256 : 512;
    constexpr int NKT = K / 32;

    __shared__ __align__(16) _Float16 Al[128 * 32];  // [row][k] linear, 64B rows
    __shared__ __align__(16) _Float16 Bl[128 * 32];  // [col][k] linear
    __shared__ __align__(16) _Float16 Ct[(MODE == 2) ? 1 : 128][136]; // epilogue stage

    const int t  = threadIdx.x;
    const int wv = t >> 6, l = t & 63;
    const int fr = l & 15, fg = l >> 4;
    const int wm = wv >> 1, wn = wv & 1;
    const long bm0 = (long)blockIdx.x * 128;
    const int  bn0 = blockIdx.y * 128;
    const int sr = t >> 2, sc = t & 3;   // staging: row-in-round, 16B chunk

    // MODE1 M-tile remap: 4 seqs x 32 p
    const int grp = blockIdx.x >> 5;           // 4-seq group (chunk-local)
    const int pp0 = (blockIdx.x & 31) * 32;

    f32x4 acc[4][4] = {};

    for (int kt = 0; kt < NKT; ++kt) {
        // ---- B staging (f16 [N][K]) via global_load_lds ----
        #pragma unroll
        for (int q = 0; q < 2; ++q) {
            const int r = q * 64 + sr;
            const _Float16* g = Bt + (long)(bn0 + r) * K + kt * 32 + sc * 8;
            gl_lds16(g, (char*)Bl + q * 4096 + wv * 1024, l);
        }
        // ---- A staging ----
        if constexpr (MODE == 0) {
            #pragma unroll
            for (int q = 0; q < 2; ++q) {
                const int r = q * 64 + sr;
                const float* xs = (const float*)Aa_ + (bm0 + r) * 256 + kt * 32 + sc * 8;
                float4 v0 = *(const float4*)xs;
                float4 v1 = *(const float4*)(xs + 4);
                h8 hv;
                hv[0] = (_Float16)v0.x; hv[1] = (_Float16)v0.y;
                hv[2] = (_Float16)v0.z; hv[3] = (_Float16)v0.w;
                hv[4] = (_Float16)v1.x; hv[5] = (_Float16)v1.y;
                hv[6] = (_Float16)v1.z; hv[7] = (_Float16)v1.w;
                *(h8*)((char*)Al + r * 64 + sc * 16) = hv;
            }
        } else if constexpr (MODE == 1) {
            #pragma unroll
            for (int q = 0; q < 2; ++q) {
                const int r = q * 64 + sr;
                const long lrow = (long)(grp * 4 + (r >> 5)) * 1024 + pp0 + (r & 31);
                const _Float16* g = (const _Float16*)Aa_ + lrow * 1024 + kt * 32 + sc * 8;
                gl_lds16(g, (char*)Al + q * 4096 + wv * 1024, l);
            }
        } else {
            const _Float16* src = (kt < 8) ? (const _Float16*)Aa_ : (const _Float16*)Ab_;
            #pragma unroll
            for (int q = 0; q < 2; ++q) {
                const int r = q * 64 + sr;
                const _Float16* g = src + (bm0 + r) * 256 + (kt & 7) * 32 + sc * 8;
                gl_lds16(g, (char*)Al + q * 4096 + wv * 1024, l);
            }
        }
        __syncthreads();

        h8 af[4], bf[4];
        #pragma unroll
        for (int fm = 0; fm < 4; ++fm)
            af[fm] = *(const h8*)((const char*)Al + (wm * 64 + fm * 16 + fr) * 64 + fg * 16);
        #pragma unroll
        for (int fn = 0; fn < 4; ++fn)
            bf[fn] = *(const h8*)((const char*)Bl + (wn * 64 + fn * 16 + fr) * 64 + fg * 16);
        #pragma unroll
        for (int fm = 0; fm < 4; ++fm)
        #pragma unroll
        for (int fn = 0; fn < 4; ++fn)
            acc[fm][fn] = __builtin_amdgcn_mfma_f32_16x16x32_f16(af[fm], bf[fn], acc[fm][fn], 0, 0, 0);
        __syncthreads();
    }

    if constexpr (MODE == 2) {
        #pragma unroll
        for (int fm = 0; fm < 4; ++fm)
        #pragma unroll
        for (int fn = 0; fn < 4; ++fn)
        #pragma unroll
        for (int r = 0; r < 4; ++r) {
            long row = bm0 + wm * 64 + fm * 16 + fg * 4 + r;
            int  col = bn0 + wn * 64 + fn * 16 + fr;
            float v = acc[fm][fn][r] + bias[col] + xres[row * 256 + col];
            ((float*)out_)[row * 256 + col] = v;
        }
    } else {
        // stage C tile (with bias / GELU) into LDS
        #pragma unroll
        for (int fm = 0; fm < 4; ++fm)
        #pragma unroll
        for (int fn = 0; fn < 4; ++fn)
        #pragma unroll
        for (int r = 0; r < 4; ++r) {
            int rowt = wm * 64 + fm * 16 + fg * 4 + r;
            int colt = wn * 64 + fn * 16 + fr;
            float v = acc[fm][fn][r] + bias[bn0 + colt];
            if constexpr (MODE == 0)
                v = 0.5f * v * (1.0f + erff(v * 0.70710678118654752f));
            Ct[rowt][colt] = (_Float16)v;
        }
        __syncthreads();

        if constexpr (MODE == 0) {
            // coalesced 16B row-major stores
            #pragma unroll
            for (int i = 0; i < 8; ++i) {
                const int row = i * 16 + (t >> 4);
                const int ch  = t & 15;
                h8 vv = *(const h8*)&Ct[row][ch * 8];
                *(h8*)((_Float16*)out_ + (bm0 + row) * 1024 + bn0 + ch * 8) = vv;
            }
        } else {
            // gather 8 e-bytes per gi slot -> dense 16B stores
            const int g    = bn0 >> 8;
            const int ci0b = (bn0 & 255) >> 5;          // base wvx
            const long gseq0 = (m_off >> 10) + grp * 4; // global first seq of tile
            const int blkg = (int)(gseq0 >> 4);
            const int srhi = ((int)gseq0 >> 2) & 3;
            #pragma unroll
            for (int i = 0; i < 8; ++i) {
                const int sid = t * 8 + i;
                const int p_local = sid >> 6;
                const int rem = sid & 63;
                const int wvl = rem >> 4, lnlow = rem & 15;
                h8 v;
                #pragma unroll
                for (int tp = 0; tp < 2; ++tp)
                #pragma unroll
                for (int s = 0; s < 4; ++s)
                    v[tp * 4 + s] = Ct[s * 32 + p_local][wvl * 32 + tp * 16 + lnlow];
                const long p = pp0 + p_local;
                const long oidx = (((long)blkg * 1024 + p) * 3 + g) * 512
                                + ((ci0b + wvl) * 64 + (srhi << 4) + lnlow);
                *(h8*)((_Float16*)out_ + oidx * 8) = v;
            }
        }
    }
}

// ---------------- prep: transpose-convert fp32 [K][N] -> f16 [N][K] --------------
__global__ __launch_bounds__(256) void k_prep_wt(
    const float* __restrict__ src, _Float16* __restrict__ dst, int Kd, int Nd)
{
    const int i = blockIdx.x * 256 + threadIdx.x;
    if (i >= Kd * Nd) return;
    const int n = i / Kd, k = i % Kd;
    dst[i] = (_Float16)src[(long)k * Nd + n];
}

// lin bias concat [1024]
__global__ __launch_bounds__(256) void k_prep_lb(
    const float* __restrict__ fb, const float* __restrict__ bb, float* __restrict__ dst)
{
    const int i = blockIdx.x * 256 + threadIdx.x;
    dst[i] = (i < 512) ? fb[i] : bb[i - 512];
}

// ---------------- prep: W_hh fp32 [256][768] -> MFMA B-fragment layout f16 --------
__global__ __launch_bounds__(256) void k_prep_frag(
    const float* __restrict__ Whh, _Float16* __restrict__ Wp)
{
    const int t = blockIdx.x * 256 + threadIdx.x;   // < 24576
    const int l = t & 63, f = t >> 6;               // f < 384
    const int kt = f & 7;
    const int q  = f >> 3;          // < 48
    const int tp = q & 1;
    const int q2 = q >> 1;          // < 24
    const int g  = q2 % 3, w = q2 / 3;
    const int col = g * 256 + w * 32 + tp * 16 + (l & 15);
    const int k0  = kt * 32 + (l >> 4) * 8;
    h8 v;
    #pragma unroll
    for (int i = 0; i < 8; ++i)
        v[i] = (_Float16)Whh[(long)(k0 + i) * 768 + col];
    ((h8*)Wp)[t] = v;
}

// bc[col] = b_ih[col] + (col<512 ? b_hh[col] : 0)  (n-gate b_hh applied inside GRU)
__global__ __launch_bounds__(256) void k_prep_bias(
    const float* __restrict__ bih, const float* __restrict__ bhh, float* __restrict__ bc)
{
    const int c = blockIdx.x * 256 + threadIdx.x;   // < 768
    bc[c] = bih[c] + (c < 512 ? bhh[c] : 0.f);
}

// ---------------- GRU recurrence v4 (unchanged from round 7/8) --------------------
__global__ __launch_bounds__(512, 2) void k_gru2(
    const _Float16* __restrict__ gpf, const _Float16* __restrict__ gpb,
    const _Float16* __restrict__ Wpf, const _Float16* __restrict__ Wpb,
    const float* __restrict__ bhhf, const float* __restrict__ bhhb,
    _Float16* __restrict__ hof, _Float16* __restrict__ hob)
{
    const int b = blockIdx.x;        // 16
    const int dir = b & 1;
    const int blk = b >> 1;          // seq-group [0,8)
    const int t = threadIdx.x;       // 512
    const int w = t >> 6, l = t & 63;
    const int lr = l & 15, lq = l >> 4;

    const _Float16* gp  = dir ? gpb : gpf;
    const _Float16* Wp  = dir ? Wpb : Wpf;
    const float*    bhh = dir ? bhhb : bhhf;
    _Float16*       hoo = dir ? hob : hof;

    __shared__ __align__(16) h8 wn_lds[8192];            // n-gate W frags 128KB
    __shared__ __align__(16) _Float16 hbuf[2][16][264];  // dbuf h, pad 256->264

    h8 bfrz[2][2][8];
    {
        const h8* src = (const h8*)Wp + (long)w * 48 * 64 + l;
        #pragma unroll
        for (int g = 0; g < 2; ++g)
        #pragma unroll
        for (int tp = 0; tp < 2; ++tp)
        #pragma unroll
        for (int kt = 0; kt < 8; ++kt)
            bfrz[g][tp][kt] = src[((g * 2 + tp) * 8 + kt) * 64];
        #pragma unroll
        for (int tp = 0; tp < 2; ++tp)
        #pragma unroll
        for (int kt = 0; kt < 8; ++kt)
            wn_lds[((w * 2 + tp) * 8 + kt) * 64 + l] = src[((4 + tp) * 8 + kt) * 64];
    }
    const int col0 = w * 32 + lr;
    const float bn0 = bhh[512 + col0];
    const float bn1 = bhh[512 + col0 + 16];

    for (int i = t; i < 2 * 16 * 264; i += 512) ((_Float16*)hbuf)[i] = (_Float16)0.f;
    __syncthreads();

    const int d = dir ? -1 : 1;
    int p = dir ? (PSEQ - 1) : 0;
    int cur = 0;
    const long tbase = (long)t * 8;
    const long bbase = (long)blk * 1024;
    float hold[2][4] = {};

    h8 gv0 = *(const h8*)(gp + ((bbase + p) * 3 + 0) * 4096 + tbase);
    h8 gv1 = *(const h8*)(gp + ((bbase + p) * 3 + 1) * 4096 + tbase);
    h8 gv2 = *(const h8*)(gp + ((bbase + p) * 3 + 2) * 4096 + tbase);

    for (int step = 0; step < PSEQ; ++step) {
        int pn = p + d;
        pn = pn < 0 ? 0 : (pn > PSEQ - 1 ? PSEQ - 1 : pn);
        h8 nv0 = *(const h8*)(gp + ((bbase + pn) * 3 + 0) * 4096 + tbase);
        h8 nv1 = *(const h8*)(gp + ((bbase + pn) * 3 + 1) * 4096 + tbase);
        h8 nv2 = *(const h8*)(gp + ((bbase + pn) * 3 + 2) * 4096 + tbase);

        h8 af[8];
        #pragma unroll
        for (int kt = 0; kt < 8; ++kt)
            af[kt] = *(const h8*)&hbuf[cur][lr][kt * 32 + lq * 8];

        f32x4 accr[2] = {}, accz[2] = {};
        #pragma unroll
        for (int kt = 0; kt < 8; ++kt) {
            #pragma unroll
            for (int tp = 0; tp < 2; ++tp) {
                accr[tp] = __builtin_amdgcn_mfma_f32_16x16x32_f16(af[kt], bfrz[0][tp][kt], accr[tp], 0, 0, 0);
                accz[tp] = __builtin_amdgcn_mfma_f32_16x16x32_f16(af[kt], bfrz[1][tp][kt], accz[tp], 0, 0, 0);
            }
        }

        float rr[2][4], zz[2][4];
        #pragma unroll
        for (int tp = 0; tp < 2; ++tp)
        #pragma unroll
        for (int r = 0; r < 4; ++r) {
            const int e = tp * 4 + r;
            rr[tp][r] = fast_sigmoid(accr[tp][r] + (float)gv0[e]);
            zz[tp][r] = fast_sigmoid(accz[tp][r] + (float)gv1[e]);
        }

        f32x4 accn[2] = {};
        #pragma unroll
        for (int kt = 0; kt < 8; ++kt) {
            h8 bfn0 = wn_lds[((w * 2 + 0) * 8 + kt) * 64 + l];
            h8 bfn1 = wn_lds[((w * 2 + 1) * 8 + kt) * 64 + l];
            accn[0] = __builtin_amdgcn_mfma_f32_16x16x32_f16(af[kt], bfn0, accn[0], 0, 0, 0);
            accn[1] = __builtin_amdgcn_mfma_f32_16x16x32_f16(af[kt], bfn1, accn[1], 0, 0, 0);
        }

        #pragma unroll
        for (int tp = 0; tp < 2; ++tp) {
            const int col = col0 + tp * 16;
            const float bn = tp ? bn1 : bn0;
            #pragma unroll
            for (int r = 0; r < 4; ++r) {
                const int e = tp * 4 + r;
                float nh = accn[tp][r] + bn;
                float nn = fast_tanh((float)gv2[e] + rr[tp][r] * nh);
                float h  = fmaf(zz[tp][r], hold[tp][r] - nn, nn);
                hold[tp][r] = h;
                _Float16 hf = (_Float16)h;
                const int row = lq * 4 + r;
                hbuf[cur ^ 1][row][col] = hf;
                hoo[((long)(blk * 16 + row) * PSEQ + p) * 256 + col] = hf;
            }
        }
        __syncthreads();

        cur ^= 1; p += d;
        gv0 = nv0; gv1 = nv1; gv2 = nv2;
    }
}

// ---------------- LayerNorm over H=256, wave per row ------------------------------
__global__ __launch_bounds__(256) void k_ln(
    const float* __restrict__ pre, const float* __restrict__ g,
    const float* __restrict__ b, float* __restrict__ out)
{
    const long row = (long)blockIdx.x * 4 + (threadIdx.x >> 6);
    const int lane = threadIdx.x & 63;
    const float4 v = *(const float4*)&pre[row * 256 + lane * 4];
    float s  = v.x + v.y + v.z + v.w;
    float s2 = v.x * v.x + v.y * v.y + v.z * v.z + v.w * v.w;
    #pragma unroll
    for (int off = 32; off > 0; off >>= 1) {
        s  += __shfl_xor(s, off);
        s2 += __shfl_xor(s2, off);
    }
    const float mu  = s * (1.f / 256.f);
    const float var = s2 * (1.f / 256.f) - mu * mu;
    const float inv = rsqrtf(var + 1e-5f);
    const float4 gg = *(const float4*)&g[lane * 4];
    const float4 bb = *(const float4*)&b[lane * 4];
    float4 o;
    o.x = (v.x - mu) * inv * gg.x + bb.x;
    o.y = (v.y - mu) * inv * gg.y + bb.y;
    o.z = (v.z - mu) * inv * gg.z + bb.z;
    o.w = (v.w - mu) * inv * gg.w + bb.w;
    *(float4*)&out[row * 256 + lane * 4] = o;
}

extern "C" void kernel_launch(void* const* d_in, const int* in_sizes, int n_in,
                              void* d_out, int out_size, void* d_ws, size_t ws_size,
                              hipStream_t stream)
{
    const float* x       = (const float*)d_in[0];
    const float* f_lin_W = (const float*)d_in[1];
    const float* f_lin_b = (const float*)d_in[2];
    const float* f_W_ih  = (const float*)d_in[3];
    const float* f_W_hh  = (const float*)d_in[4];
    const float* f_b_ih  = (const float*)d_in[5];
    const float* f_b_hh  = (const float*)d_in[6];
    const float* b_lin_W = (const float*)d_in[7];
    const float* b_lin_b = (const float*)d_in[8];
    const float* b_W_ih  = (const float*)d_in[9];
    const float* b_W_hh  = (const float*)d_in[10];
    const float* b_b_ih  = (const float*)d_in[11];
    const float* b_b_hh  = (const float*)d_in[12];
    const float* proj_W  = (const float*)d_in[13];
    const float* proj_b  = (const float*)d_in[14];
    const float* ln_g    = (const float*)d_in[15];
    const float* ln_bb   = (const float*)d_in[16];

    char* ws = (char*)d_ws;

    // ws: [weights/bias preps < 4MB | gi_f 192M | gi_b 192M | h1cat chunk]
    // pre-LN fp32 (128MB) aliases gi_f (gi dead by MODE 2).
    // h_out f16 (both dirs, 128MB) lives in d_out (fully overwritten by k_ln).
    size_t o = 0;
    _Float16* wt_lin  = (_Float16*)(ws + o); o += 1024 * 256 * 2;   // 512K
    _Float16* wt_ihf  = (_Float16*)(ws + o); o += 768 * 512 * 2;    // 768K
    _Float16* wt_ihb  = (_Float16*)(ws + o); o += 768 * 512 * 2;
    _Float16* wt_proj = (_Float16*)(ws + o); o += 256 * 512 * 2;    // 256K
    float*    bl_lin  = (float*)(ws + o);    o += 1024 * 4;
    float*    bcf     = (float*)(ws + o);    o += 768 * 4;
    float*    bcb     = (float*)(ws + o);    o += 768 * 4;
    _Float16* wpf     = (_Float16*)(ws + o); o += 393216;
    _Float16* wpb     = (_Float16*)(ws + o); o += 393216;

    const size_t BASE   = 4u << 20;
    const size_t GI_PER = (size_t)MTOT * 768 * 2;          // 192MB
    const size_t GI_END = BASE + 2 * GI_PER;               // 388MB
    int chunks = 1;
    while (GI_END + (size_t)(MTOT / chunks) * 1024 * 2 > ws_size && chunks < 16)
        chunks <<= 1;
    const long MC = MTOT / chunks;

    _Float16* gif   = (_Float16*)(ws + BASE);
    _Float16* gib   = (_Float16*)(ws + BASE + GI_PER);
    float*    pre   = (float*)(ws + BASE);
    _Float16* h1cat = (_Float16*)(ws + GI_END);

    _Float16* hof = (_Float16*)d_out;
    _Float16* hob = hof + MTOT * 256;

    // ---- weight preps (one-time, tiny) ----
    k_prep_wt<<<512,  256, 0, stream>>>(f_lin_W, wt_lin,             256, 512);
    k_prep_wt<<<512,  256, 0, stream>>>(b_lin_W, wt_lin + 512 * 256, 256, 512);
    k_prep_wt<<<1536, 256, 0, stream>>>(f_W_ih,  wt_ihf,             512, 768);
    k_prep_wt<<<1536, 256, 0, stream>>>(b_W_ih,  wt_ihb,             512, 768);
    k_prep_wt<<<512,  256, 0, stream>>>(proj_W,  wt_proj,            512, 256);
    k_prep_lb<<<4,    256, 0, stream>>>(f_lin_b, b_lin_b, bl_lin);
    k_prep_bias<<<3,  256, 0, stream>>>(f_b_ih, f_b_hh, bcf);
    k_prep_bias<<<3,  256, 0, stream>>>(b_b_ih, b_b_hh, bcb);
    k_prep_frag<<<96, 256, 0, stream>>>(f_W_hh, wpf);
    k_prep_frag<<<96, 256, 0, stream>>>(b_W_hh, wpb);

    // ---- position-wise front GEMMs, M-chunked ----
    for (int c = 0; c < chunks; ++c) {
        const long r0 = c * MC;
        k_gemm2<0><<<dim3(MC / 128, 8), 256, 0, stream>>>(
            x + r0 * 256, nullptr, wt_lin, bl_lin, nullptr, h1cat, 0L);
        k_gemm2<1><<<dim3(MC / 128, 6), 256, 0, stream>>>(
            h1cat, nullptr, wt_ihf, bcf, nullptr, gif, r0);
        k_gemm2<1><<<dim3(MC / 128, 6), 256, 0, stream>>>(
            h1cat + 512, nullptr, wt_ihb, bcb, nullptr, gib, r0);
    }
    k_gru2<<<16, 512, 0, stream>>>(gif, gib, wpf, wpb, f_b_hh, b_b_hh, hof, hob);
    k_gemm2<2><<<dim3(MTOT / 128, 2), 256, 0, stream>>>(
        hof, hob, wt_proj, proj_b, x, pre, 0L);
    k_ln<<<MTOT / 4, 256, 0, stream>>>(pre, ln_g, ln_bb, (float*)d_out);
}